// Round 6
// baseline (148.961 us; speedup 1.0000x reference)
//
#include <hip/hip_runtime.h>

#define IN_DIM 256
#define OUT_DIM 128
#define LEAKY 0.01f

typedef __attribute__((ext_vector_type(8))) short bf16x8;
typedef __attribute__((ext_vector_type(4))) float f32x4;

// RNE f32->bf16 pack (2 at a time). No builtin on gfx950 -> inline asm.
__device__ inline unsigned cvtpk_bf16(float lo, float hi) {
  unsigned r;
  asm volatile("v_cvt_pk_bf16_f32 %0, %1, %2" : "=v"(r) : "v"(lo), "v"(hi));
  return r;
}

__device__ inline float b2f(unsigned short u) {
  union { unsigned u; float f; } c;
  c.u = ((unsigned)u) << 16;
  return c.f;
}

// ---------------------------------------------------------------------------
// Kernel 0a: weight fp32 [128*256] -> bf16 bits.
// ---------------------------------------------------------------------------
__global__ __launch_bounds__(256) void wcvt(const float* __restrict__ w,
                                            unsigned* __restrict__ wbf) {
  int i = blockIdx.x * 256 + threadIdx.x;  // 16384 = 128*256/2
  float2 v = reinterpret_cast<const float2*>(w)[i];
  wbf[i] = cvtpk_bf16(v.x, v.y);
}

// ---------------------------------------------------------------------------
// Kernel 0b: row_starts[r] = lower_bound(erows, r); rs[nrows] = nedges.
// ---------------------------------------------------------------------------
__global__ __launch_bounds__(256) void row_bounds(const int* __restrict__ erows,
                                                  int* __restrict__ rs,
                                                  int nrows, int nedges) {
  int r = blockIdx.x * 256 + threadIdx.x;
  if (r > nrows) return;
  if (r == nrows) { rs[nrows] = nedges; return; }
  int lo = 0, hi = nedges;
  while (lo < hi) {
    int mid = (lo + hi) >> 1;
    if (erows[mid] < r) lo = mid + 1; else hi = mid;
  }
  rs[r] = lo;
}

// ---------------------------------------------------------------------------
// Kernel 1: support(bf16) = LeakyReLU(features @ W^T) via bf16 MFMA.
// 256 thr / 4 waves, 128 rows/block; wave = 32 rows (2x16 stripes) x 128 cols.
// K=256 processed in TWO halves of 128 floats, single 32 KB LDS buffer
// reused (stage h -> sync -> mfma h -> sync) => 5 blocks/CU by LDS
// (R4's 64 KB tile capped at 2 blocks/CU -> 15% occupancy -> latency-bound).
// Swizzle (measured 0 bank conflicts in R4): 16B unit u of row r stored at
//   byte = r*256 + ((u ^ (r&15)) << 4)
// W (bf16, 64 KB) direct from global: L2-hot, each fragment reused 2x.
// ---------------------------------------------------------------------------
__global__ __launch_bounds__(256, 4) void gemm_mfma(
    const float* __restrict__ feat, const unsigned short* __restrict__ wbf,
    unsigned short* __restrict__ support, int nrows) {
  __shared__ alignas(16) unsigned short fbuf[128 * 128];  // 32 KB
  char* fb = reinterpret_cast<char*>(fbuf);

  const int t    = threadIdx.x;
  const int row0 = blockIdx.x * 128;
  const int wid  = t >> 6;
  const int lane = t & 63;
  const int lrow = lane & 15;
  const int hi   = lane >> 4;

  const unsigned short* wp = wbf + lrow * IN_DIM + hi * 8;

  f32x4 acc[2][8];
#pragma unroll
  for (int s = 0; s < 2; ++s)
#pragma unroll
    for (int nt = 0; nt < 8; ++nt) acc[s][nt] = (f32x4){0.f, 0.f, 0.f, 0.f};

#pragma unroll
  for (int h = 0; h < 2; ++h) {
    if (h) __syncthreads();  // protect LDS reuse between halves
    // stage K-half h: 128 rows x 128 floats, coalesced (16 thr = 512B row-half)
#pragma unroll
    for (int it = 0; it < 8; ++it) {
      const int g  = it * 256 + t;  // 0..2047
      const int r  = g >> 4;        // 0..127
      const int cu = g & 15;        // 16B unit within half-row
      int gr = row0 + r;
      if (gr >= nrows) gr = nrows - 1;
      const float* src = &feat[gr * IN_DIM + h * 128 + cu * 8];
      const float4 a = *reinterpret_cast<const float4*>(src);
      const float4 b = *reinterpret_cast<const float4*>(src + 4);
      uint4 pk;
      pk.x = cvtpk_bf16(a.x, a.y);
      pk.y = cvtpk_bf16(a.z, a.w);
      pk.z = cvtpk_bf16(b.x, b.y);
      pk.w = cvtpk_bf16(b.z, b.w);
      const int byte = r * 256 + ((cu ^ (r & 15)) << 4);
      *reinterpret_cast<uint4*>(fb + byte) = pk;
    }
    __syncthreads();

#pragma unroll
    for (int ks = 0; ks < 4; ++ks) {
      const int cu = ks * 4 + hi;
      bf16x8 b[2];
#pragma unroll
      for (int s = 0; s < 2; ++s) {
        const int rl   = wid * 32 + s * 16 + lrow;
        const int byte = rl * 256 + ((cu ^ (rl & 15)) << 4);
        b[s] = *reinterpret_cast<const bf16x8*>(fb + byte);
      }
#pragma unroll
      for (int nt = 0; nt < 8; ++nt) {
        const bf16x8 af = *reinterpret_cast<const bf16x8*>(
            wp + nt * 16 * IN_DIM + h * 128 + ks * 32);
        acc[0][nt] = __builtin_amdgcn_mfma_f32_16x16x32_bf16(af, b[0],
                                                             acc[0][nt], 0, 0, 0);
        acc[1][nt] = __builtin_amdgcn_mfma_f32_16x16x32_bf16(af, b[1],
                                                             acc[1][nt], 0, 0, 0);
      }
    }
  }

#pragma unroll
  for (int s = 0; s < 2; ++s) {
    const int mrow = row0 + wid * 32 + s * 16 + lrow;
    if (mrow < nrows) {
      unsigned short* orow = support + mrow * OUT_DIM + hi * 4;
#pragma unroll
      for (int nt = 0; nt < 8; ++nt) {
        f32x4 v = acc[s][nt];
        float a0 = v[0] > 0.f ? v[0] : LEAKY * v[0];
        float a1 = v[1] > 0.f ? v[1] : LEAKY * v[1];
        float a2 = v[2] > 0.f ? v[2] : LEAKY * v[2];
        float a3 = v[3] > 0.f ? v[3] : LEAKY * v[3];
        uint2 st;
        st.x = cvtpk_bf16(a0, a1);
        st.y = cvtpk_bf16(a2, a3);
        *reinterpret_cast<uint2*>(orow + nt * 16) = st;
      }
    }
  }
}

// ---------------------------------------------------------------------------
// Kernel 2: out[r] = sum over edges (r,c,v) of v * support_bf16[c]
// 256 threads = 8 rows x 32 lanes; lane owns 4 cols (8B ushort4 gathers).
// Per 32-edge batch: ONE vector load of cols + ONE of vals per group, then
// __shfl broadcast -> gather addresses never wait on an index load; the 8
// gathers per unroll-batch issue back-to-back. Padded lanes: v=0, col
// clamped to batch start (L1-hit, x0). Nontemporal out store keeps the
// 51 MB write from evicting the hot support table in L2.
// ---------------------------------------------------------------------------
__global__ __launch_bounds__(256) void spmm_bf16(
    const int* __restrict__ rs, const int* __restrict__ ecols,
    const float* __restrict__ evals, const unsigned short* __restrict__ support,
    float* __restrict__ out, int nrows) {
  const int t    = threadIdx.x;
  const int lane = t & 31;
  const int row  = blockIdx.x * 8 + (t >> 5);
  if (row >= nrows) return;

  const int s = rs[row];
  const int e = rs[row + 1];

  f32x4 acc[8];
#pragma unroll
  for (int j = 0; j < 8; ++j) acc[j] = (f32x4){0.f, 0.f, 0.f, 0.f};

  for (int base = s; base < e; base += 32) {
    const int rem = e - base;  // > 0
    const int li  = base + (lane < rem ? lane : 0);
    const int   ci = ecols[li];
    const float vi = lane < rem ? evals[li] : 0.f;
    const int n = rem < 32 ? rem : 32;
    for (int j = 0; j < n; j += 8) {
#pragma unroll
      for (int q = 0; q < 8; ++q) {
        const int   c = __shfl(ci, j + q, 32);
        const float v = __shfl(vi, j + q, 32);
        const ushort4 u =
            *reinterpret_cast<const ushort4*>(&support[c * OUT_DIM + lane * 4]);
        acc[q].x += v * b2f(u.x);
        acc[q].y += v * b2f(u.y);
        acc[q].z += v * b2f(u.z);
        acc[q].w += v * b2f(u.w);
      }
    }
  }

#pragma unroll
  for (int j = 1; j < 8; ++j) {
    acc[0].x += acc[j].x;
    acc[0].y += acc[j].y;
    acc[0].z += acc[j].z;
    acc[0].w += acc[j].w;
  }
  __builtin_nontemporal_store(
      acc[0], reinterpret_cast<f32x4*>(&out[row * OUT_DIM + lane * 4]));
}

// ---------------------------------------------------------------------------
extern "C" void kernel_launch(void* const* d_in, const int* in_sizes, int n_in,
                              void* d_out, int out_size, void* d_ws,
                              size_t ws_size, hipStream_t stream) {
  const float* features = (const float*)d_in[0];
  const float* weight   = (const float*)d_in[1];
  const int*   erows    = (const int*)d_in[2];
  const int*   ecols    = (const int*)d_in[3];
  const float* evals    = (const float*)d_in[4];
  float*       out      = (float*)d_out;

  const int nrows  = in_sizes[0] / IN_DIM;  // 100000
  const int nedges = in_sizes[2];           // 1600000

  // ws layout: support bf16 (25.6 MB) | wbf16 (64 KB) | row_starts (400 KB)
  unsigned short* support = (unsigned short*)d_ws;
  unsigned short* wbf =
      (unsigned short*)((char*)d_ws + (size_t)nrows * OUT_DIM * 2);
  int* rs = (int*)((char*)wbf + (size_t)OUT_DIM * IN_DIM * 2);

  wcvt<<<64, 256, 0, stream>>>(weight, (unsigned*)wbf);
  row_bounds<<<(nrows + 256) / 256, 256, 0, stream>>>(erows, rs, nrows, nedges);
  gemm_mfma<<<(nrows + 127) / 128, 256, 0, stream>>>(features, wbf, support,
                                                     nrows);
  spmm_bf16<<<(nrows + 7) / 8, 256, 0, stream>>>(rs, ecols, evals, support,
                                                 out, nrows);
}